// Round 14
// baseline (263.958 us; speedup 1.0000x reference)
//
#include <hip/hip_runtime.h>
#include <hip/hip_bf16.h>
#include <hip/hip_fp16.h>

// coif4 decomposition low-pass filter (L=24), fp32
constexpr int L = 24;
__device__ __constant__ float DEC_LO[L] = {
    -1.7849850030882614e-06f, -3.2596802368833675e-06f, 3.1229875865345646e-05f,
    6.233903446100713e-05f, -0.00025997455248771324f, -0.0005890207562443383f,
    0.0012665619292989445f, 0.003751436157278457f, -0.00565828668661072f,
    -0.015211731527946259f, 0.025082261844864097f, 0.03933442712333749f,
    -0.09622044203398798f, -0.06662747426342504f, 0.4343860564914685f,
    0.782238930920499f, 0.41530840703043026f, -0.05607731331675481f,
    -0.08126669968087875f, 0.026682300156053072f, 0.016068943964776348f,
    -0.0073461663276420935f, -0.0016294920126017326f, 0.0008923136685823146f
};

__device__ __forceinline__ float g0f(int m) { return DEC_LO[23 - m]; }
__device__ __forceinline__ float g1f(int m) { return (m & 1) ? -DEC_LO[m] : DEC_LO[m]; }

// ---------------- L1: merged col-pass (A and B in one dispatch, z selects) ----------------
__global__ void colpass2_kernel(const float* __restrict__ lowA, const float* __restrict__ highA,
                                float sLA, float sHA, int lACS, int hACS,
                                const float* __restrict__ lowB, const float* __restrict__ highB,
                                float sLB, float sHB, int lBCS, int hBCS,
                                int n, int W,
                                float* __restrict__ outA, float* __restrict__ outB)
{
    int x = blockIdx.x * 64 + threadIdx.x;
    int q = blockIdx.y * blockDim.y + threadIdx.y;
    int z = blockIdx.z;
    int c = z & 31;
    bool isB = z >= 32;                  // block-uniform
    const float* low  = isB ? lowB  : lowA;
    const float* high = isB ? highB : highA;
    float sLow  = isB ? sLB : sLA;
    float sHigh = isB ? sHB : sHA;
    int lowCS  = isB ? lBCS : lACS;
    int highCS = isB ? hBCS : hACS;
    float* out = isB ? outB : outA;

    int mask = n - 1;
    const float* lp = low + (size_t)c * lowCS + x;
    const float* hp = high + (size_t)c * highCS + x;
    float a0 = 0.f, a1 = 0.f;
#pragma unroll
    for (int s = 0; s <= 12; ++s) {
        int r = (q + 6 - s) & mask;
        float lv = sLow * lp[(size_t)r * W];
        float hv = sHigh * hp[(size_t)r * W];
        if (s >= 1)  a0 = fmaf(g0f(2 * s - 1), lv, fmaf(g1f(2 * s - 1), hv, a0));
        if (s <= 11) a1 = fmaf(g0f(2 * s), lv, fmaf(g1f(2 * s), hv, a1));
    }
    size_t ob = ((size_t)c * (2 * n) + 2 * q) * W + x;
    out[ob] = a0;
    out[ob + W] = a1;
}

__global__ void rowpass_kernel(const float* __restrict__ lo, const float* __restrict__ hi,
                               int n, float* __restrict__ out)
{
    int q = blockIdx.x * 64 + threadIdx.x;
    int y = blockIdx.y * blockDim.y + threadIdx.y;
    int c = blockIdx.z;
    int N = 2 * n, mask = n - 1;
    const float* lp = lo + ((size_t)c * N + y) * n;
    const float* hp = hi + ((size_t)c * N + y) * n;
    float a0 = 0.f, a1 = 0.f;
#pragma unroll
    for (int s = 0; s <= 12; ++s) {
        int r = (q + 6 - s) & mask;
        float lv = lp[r];
        float hv = hp[r];
        if (s >= 1)  a0 = fmaf(g0f(2 * s - 1), lv, fmaf(g1f(2 * s - 1), hv, a0));
        if (s <= 11) a1 = fmaf(g0f(2 * s), lv, fmaf(g1f(2 * s), hv, a1));
    }
    float2* op = (float2*)(out + ((size_t)c * N + y) * N + 2 * q);
    *op = make_float2(a0, a1);
}

// ---------------- L2 merged col-pass: register-blocked 4 q-pairs/thread, fp16 out ----------------
// n=256: float4 over x (W4=64), 16-row union window, out (32,512,256) fp16.
__global__ void colpass4h2c_kernel(const float4* __restrict__ loA, const float4* __restrict__ hiA,
                                   float sLA, float sHA, int lACS4, int hACS4,
                                   const float4* __restrict__ loB, const float4* __restrict__ hiB,
                                   float sLB, float sHB, int lBCS4, int hBCS4,
                                   __half* __restrict__ outA, __half* __restrict__ outB)
{
    const int mask = 255, W4 = 64;
    int x = threadIdx.x;                                // [0,64) f4 index, full row
    int q0 = (blockIdx.y * 4 + threadIdx.y) * 4;        // 4 q-pairs per thread
    int z = blockIdx.z;
    int c = z & 31;
    bool isB = z >= 32;
    const float4* lo = isB ? loB : loA;
    const float4* hi = isB ? hiB : hiA;
    float sLow  = isB ? sLB : sLA;
    float sHigh = isB ? sHB : sHA;
    int loCS4 = isB ? lBCS4 : lACS4;
    int hiCS4 = isB ? hBCS4 : hACS4;
    __half* out = isB ? outB : outA;

    const float4* lp = lo + (size_t)c * loCS4 + x;
    const float4* hp = hi + (size_t)c * hiCS4 + x;

    float4 a0[4], a1[4];
#pragma unroll
    for (int j = 0; j < 4; ++j) {
        a0[j] = make_float4(0.f, 0.f, 0.f, 0.f);
        a1[j] = make_float4(0.f, 0.f, 0.f, 0.f);
    }
#pragma unroll
    for (int ro = 0; ro < 16; ++ro) {
        int r = (q0 - 6 + ro) & mask;
        float4 lv = lp[(size_t)r * W4];
        float4 hv = hp[(size_t)r * W4];
        lv.x *= sLow;  lv.y *= sLow;  lv.z *= sLow;  lv.w *= sLow;
        hv.x *= sHigh; hv.y *= sHigh; hv.z *= sHigh; hv.w *= sHigh;
#pragma unroll
        for (int j = 0; j < 4; ++j) {
            int s = j + 12 - ro;
            if (s >= 1 && s <= 12) {
                float gl = g0f(2 * s - 1), gh = g1f(2 * s - 1);
                a0[j].x = fmaf(gl, lv.x, fmaf(gh, hv.x, a0[j].x));
                a0[j].y = fmaf(gl, lv.y, fmaf(gh, hv.y, a0[j].y));
                a0[j].z = fmaf(gl, lv.z, fmaf(gh, hv.z, a0[j].z));
                a0[j].w = fmaf(gl, lv.w, fmaf(gh, hv.w, a0[j].w));
            }
            if (s >= 0 && s <= 11) {
                float gl = g0f(2 * s), gh = g1f(2 * s);
                a1[j].x = fmaf(gl, lv.x, fmaf(gh, hv.x, a1[j].x));
                a1[j].y = fmaf(gl, lv.y, fmaf(gh, hv.y, a1[j].y));
                a1[j].z = fmaf(gl, lv.z, fmaf(gh, hv.z, a1[j].z));
                a1[j].w = fmaf(gl, lv.w, fmaf(gh, hv.w, a1[j].w));
            }
        }
    }
#pragma unroll
    for (int j = 0; j < 4; ++j) {
        size_t ob = ((size_t)c * 512 + 2 * (q0 + j)) * 256 + 4 * x;   // halves
        __half2 p0 = __floats2half2_rn(a0[j].x, a0[j].y), p1 = __floats2half2_rn(a0[j].z, a0[j].w);
        __half2 p2 = __floats2half2_rn(a1[j].x, a1[j].y), p3 = __floats2half2_rn(a1[j].z, a1[j].w);
        *(uint2*)&out[ob]       = make_uint2(*(unsigned int*)&p0, *(unsigned int*)&p1);
        *(uint2*)&out[ob + 256] = make_uint2(*(unsigned int*)&p2, *(unsigned int*)&p3);
    }
}

// ---------------- L2 rowpass: fp16 in (32,512,256) -> fp16 out (32,512,512) ----------------
// Vectorized: 8 q per thread via 3x16B window loads; 32B coalesced stores.
__global__ void rowpass16c_kernel(const __half* __restrict__ lo, const __half* __restrict__ hi,
                                  __half* __restrict__ out)
{
    const int n = 256, mask = 255;
    int tid = blockIdx.x * 256 + threadIdx.x;
    int qo = tid & 31;            // q-octet index, 32 per row
    int y  = (tid >> 5) & 511;
    int c  = tid >> 14;
    int q0 = qo * 8;
    const __half* lp = lo + ((size_t)c * 512 + y) * n;
    const __half* hp = hi + ((size_t)c * 512 + y) * n;

    float wlo[24], whi[24];
#pragma unroll
    for (int k = 0; k < 3; ++k) {
        int s0 = (q0 - 8 + 8 * k) & mask;      // multiple of 8 -> 16B aligned
        float4 vl = *(const float4*)(lp + s0);
        float4 vh = *(const float4*)(hp + s0);
        const __half2* hl = (const __half2*)&vl;
        const __half2* hh = (const __half2*)&vh;
#pragma unroll
        for (int j = 0; j < 4; ++j) {
            float2 fl = __half22float2(hl[j]);
            float2 fh = __half22float2(hh[j]);
            wlo[k * 8 + 2 * j]     = fl.x;
            wlo[k * 8 + 2 * j + 1] = fl.y;
            whi[k * 8 + 2 * j]     = fh.x;
            whi[k * 8 + 2 * j + 1] = fh.y;
        }
    }

    unsigned int w[8];
#pragma unroll
    for (int j = 0; j < 8; ++j) {
        float a0 = 0.f, a1 = 0.f;
#pragma unroll
        for (int s = 0; s <= 12; ++s) {
            int li = j + 14 - s;
            float lv = wlo[li];
            float hv = whi[li];
            if (s >= 1)  a0 = fmaf(g0f(2 * s - 1), lv, fmaf(g1f(2 * s - 1), hv, a0));
            if (s <= 11) a1 = fmaf(g0f(2 * s), lv, fmaf(g1f(2 * s), hv, a1));
        }
        __half2 p = __floats2half2_rn(a0, a1);
        w[j] = *(unsigned int*)&p;
    }
    __half* ob = out + ((size_t)c * 512 + y) * 512 + 2 * q0;
    *(uint4*)ob       = make_uint4(w[0], w[1], w[2], w[3]);
    *(uint4*)(ob + 8) = make_uint4(w[4], w[5], w[6], w[7]);
}

// ---------------- Level-3 merged col-pass: 8 q-pairs/thread, mixed lo type ----------------
// A branch: lo = llbuf fp16 (32,512,512); B branch: lo = yh0-HL fp32. hi always fp32.
__global__ void colpass8h2m_kernel(const __half* __restrict__ loAh, const float4* __restrict__ hiA,
                                   float sLA, float sHA, int hACS4,
                                   const float4* __restrict__ loB, const float4* __restrict__ hiB,
                                   float sLB, float sHB, int lBCS4, int hBCS4,
                                   __half* __restrict__ outA, __half* __restrict__ outB)
{
    const int mask = 511, W4 = 128;
    int x = blockIdx.x * 64 + threadIdx.x;              // float4/uint2 index, [0,128)
    int q0 = (blockIdx.y * 4 + threadIdx.y) * 8;        // 8 q-pairs per thread
    int z = blockIdx.z;
    int c = z & 31;
    bool isB = z >= 32;
    const float4* hi = isB ? hiB : hiA;
    float sLow  = isB ? sLB : sLA;
    float sHigh = isB ? sHB : sHA;
    int hiCS4 = isB ? hBCS4 : hACS4;
    __half* out = isB ? outB : outA;

    const uint2*  lpA = (const uint2*)loAh + (size_t)c * 65536 + x;   // 512*512/4 uint2 per ch
    const float4* lpB = loB + (size_t)c * lBCS4 + x;
    const float4* hp  = hi + (size_t)c * hiCS4 + x;

    float4 a0[8], a1[8];
#pragma unroll
    for (int j = 0; j < 8; ++j) {
        a0[j] = make_float4(0.f, 0.f, 0.f, 0.f);
        a1[j] = make_float4(0.f, 0.f, 0.f, 0.f);
    }
    // Union window of rows for q0..q0+7: r = q0-6 .. q0+13 (20 rows).
#pragma unroll
    for (int ro = 0; ro < 20; ++ro) {
        int r = (q0 - 6 + ro) & mask;
        float4 lv;
        if (isB) {
            lv = lpB[(size_t)r * W4];
        } else {
            uint2 u = lpA[(size_t)r * 128];
            __half2 h0 = *(__half2*)&u.x, h1 = *(__half2*)&u.y;
            float2 f0 = __half22float2(h0), f1 = __half22float2(h1);
            lv = make_float4(f0.x, f0.y, f1.x, f1.y);
        }
        float4 hv = hp[(size_t)r * W4];
        lv.x *= sLow;  lv.y *= sLow;  lv.z *= sLow;  lv.w *= sLow;
        hv.x *= sHigh; hv.y *= sHigh; hv.z *= sHigh; hv.w *= sHigh;
#pragma unroll
        for (int j = 0; j < 8; ++j) {
            int s = j + 12 - ro;
            if (s >= 1 && s <= 12) {
                float gl = g0f(2 * s - 1), gh = g1f(2 * s - 1);
                a0[j].x = fmaf(gl, lv.x, fmaf(gh, hv.x, a0[j].x));
                a0[j].y = fmaf(gl, lv.y, fmaf(gh, hv.y, a0[j].y));
                a0[j].z = fmaf(gl, lv.z, fmaf(gh, hv.z, a0[j].z));
                a0[j].w = fmaf(gl, lv.w, fmaf(gh, hv.w, a0[j].w));
            }
            if (s >= 0 && s <= 11) {
                float gl = g0f(2 * s), gh = g1f(2 * s);
                a1[j].x = fmaf(gl, lv.x, fmaf(gh, hv.x, a1[j].x));
                a1[j].y = fmaf(gl, lv.y, fmaf(gh, hv.y, a1[j].y));
                a1[j].z = fmaf(gl, lv.z, fmaf(gh, hv.z, a1[j].z));
                a1[j].w = fmaf(gl, lv.w, fmaf(gh, hv.w, a1[j].w));
            }
        }
    }
#pragma unroll
    for (int j = 0; j < 8; ++j) {
        size_t ob = ((size_t)c * 1024 + 2 * (q0 + j)) * 512 + 4 * x;
        __half2 p0 = __floats2half2_rn(a0[j].x, a0[j].y), p1 = __floats2half2_rn(a0[j].z, a0[j].w);
        __half2 p2 = __floats2half2_rn(a1[j].x, a1[j].y), p3 = __floats2half2_rn(a1[j].z, a1[j].w);
        *(uint2*)&out[ob]       = make_uint2(*(unsigned int*)&p0, *(unsigned int*)&p1);
        *(uint2*)&out[ob + 512] = make_uint2(*(unsigned int*)&p2, *(unsigned int*)&p3);
    }
}

// ---------------- Level-3 rowpass fused with HWC output (unchanged) ----------------
__global__ void rowpass16_hwc_kernel(const __half* __restrict__ lo, const __half* __restrict__ hi,
                                     __half* __restrict__ out)
{
    const int n = 512, N = 1024, mask = 511;
    int y = blockIdx.y;
    int qb = blockIdx.x * 64;
    int t = threadIdx.x;
    int c = t >> 3;
    int tq = t & 7;
    int q0 = qb + tq * 8;

    const __half* lp = lo + ((size_t)c * N + y) * n;
    const __half* hp = hi + ((size_t)c * N + y) * n;

    float wlo[24], whi[24];
#pragma unroll
    for (int k = 0; k < 3; ++k) {
        int s0 = (q0 - 8 + 8 * k) & mask;
        float4 vl = *(const float4*)(lp + s0);
        float4 vh = *(const float4*)(hp + s0);
        const __half2* hl = (const __half2*)&vl;
        const __half2* hh = (const __half2*)&vh;
#pragma unroll
        for (int j = 0; j < 4; ++j) {
            float2 fl = __half22float2(hl[j]);
            float2 fh = __half22float2(hh[j]);
            wlo[k * 8 + 2 * j]     = fl.x;
            wlo[k * 8 + 2 * j + 1] = fl.y;
            whi[k * 8 + 2 * j]     = fh.x;
            whi[k * 8 + 2 * j + 1] = fh.y;
        }
    }

    __shared__ __half tile[128][34];

#pragma unroll
    for (int j = 0; j < 8; ++j) {
        float a0 = 0.f, a1 = 0.f;
#pragma unroll
        for (int s = 0; s <= 12; ++s) {
            int li = j + 14 - s;
            float lv = wlo[li];
            float hv = whi[li];
            if (s >= 1)  a0 = fmaf(g0f(2 * s - 1), lv, fmaf(g1f(2 * s - 1), hv, a0));
            if (s <= 11) a1 = fmaf(g0f(2 * s), lv, fmaf(g1f(2 * s), hv, a1));
        }
        int pl = 16 * tq + 2 * j;
        tile[pl][c]     = __float2half_rn(a0);
        tile[pl + 1][c] = __float2half_rn(a1);
    }
    __syncthreads();

    int p = t >> 1;
    int c0 = (t & 1) * 16;
    unsigned int w[8];
#pragma unroll
    for (int k = 0; k < 8; ++k) {
        unsigned int l16 = __half_as_ushort(tile[p][c0 + 2 * k]);
        unsigned int h16 = __half_as_ushort(tile[p][c0 + 2 * k + 1]);
        w[k] = l16 | (h16 << 16);
    }
    size_t ob = ((size_t)y * 1024 + 2 * qb + p) * 32 + c0;
    *(uint4*)&out[ob]       = make_uint4(w[0], w[1], w[2], w[3]);
    *(uint4*)(&out[ob + 8]) = make_uint4(w[4], w[5], w[6], w[7]);
}

// ---------------- Sampler: 4 threads/point, 8 channels each (best measured config) ----------------
struct alignas(16) HV { __half2 h[4]; };

__global__ __launch_bounds__(256) void sample_kernel(const float* __restrict__ pts,
                                                     const __half* __restrict__ plane,
                                                     float* __restrict__ out, int npts)
{
    int tid = blockIdx.x * 256 + threadIdx.x;
    int p = tid >> 2, cg = (tid & 3) * 8;
    float2 pt = *(const float2*)(pts + 2 * p);
    float xf = fminf(fmaxf((pt.x + 1.f) * 0.5f * 1023.f, 0.f), 1023.f);
    float yf = fminf(fmaxf((pt.y + 1.f) * 0.5f * 1023.f, 0.f), 1023.f);
    int x0 = (int)xf, y0 = (int)yf;
    int x1 = min(x0 + 1, 1023), y1 = min(y0 + 1, 1023);
    float wx = xf - (float)x0, wy = yf - (float)y0;
    size_t r0 = (size_t)y0 * 1024, r1 = (size_t)y1 * 1024;
    HV v00 = *(const HV*)(plane + (r0 + x0) * 32 + cg);
    HV v01 = *(const HV*)(plane + (r0 + x1) * 32 + cg);
    HV v10 = *(const HV*)(plane + (r1 + x0) * 32 + cg);
    HV v11 = *(const HV*)(plane + (r1 + x1) * 32 + cg);
    float o[8];
#pragma unroll
    for (int k = 0; k < 4; ++k) {
        float2 f00 = __half22float2(v00.h[k]);
        float2 f01 = __half22float2(v01.h[k]);
        float2 f10 = __half22float2(v10.h[k]);
        float2 f11 = __half22float2(v11.h[k]);
        o[2 * k]     = (f00.x * (1.f - wx) + f01.x * wx) * (1.f - wy)
                     + (f10.x * (1.f - wx) + f11.x * wx) * wy;
        o[2 * k + 1] = (f00.y * (1.f - wx) + f01.y * wx) * (1.f - wy)
                     + (f10.y * (1.f - wx) + f11.y * wx) * wy;
    }
    float* ob = out + (size_t)p * 32 + cg;
    *(float4*)ob       = make_float4(o[0], o[1], o[2], o[3]);
    *(float4*)(ob + 4) = make_float4(o[4], o[5], o[6], o[7]);
}

extern "C" void kernel_launch(void* const* d_in, const int* in_sizes, int n_in,
                              void* d_out, int out_size, void* d_ws, size_t ws_size,
                              hipStream_t stream)
{
    const float* pts = (const float*)d_in[0];
    const float* yl  = (const float*)d_in[1];
    const float* yh0 = (const float*)d_in[2]; // (32,3,512,512), scale 0.2, level 3
    const float* yh1 = (const float*)d_in[3]; // (32,3,256,256), scale 0.4, level 2
    const float* yh2 = (const float*)d_in[4]; // (32,3,128,128), scale 0.6, level 1
    const int npts = in_sizes[0] / 2;

    // Workspace layout (bytes), total 167.8 MB:
    //   [0,          33554432)  llbuf fp32 (L1 out, 8.4MB) then llbuf2h fp16 (L2 out, 16.8MB)
    //   [33554432,   67108864)  tmpA  fp32 (L1) / fp16 (L2: 8.4MB, L3: 33.5MB)
    //   [67108864,  100663296)  tmpB  same
    //   [100663296, 167772160)  planeHWC fp16 (1024,1024,32)
    char* ws = (char*)d_ws;
    float*  llbuf    = (float*)ws;
    __half* llbuf2h  = (__half*)ws;           // aliases llbuf; llbuf dead when written
    float*  tmpA     = (float*)(ws + 33554432);
    float*  tmpB     = (float*)(ws + 67108864);
    __half* tmpAh    = (__half*)(ws + 33554432);
    __half* tmpBh    = (__half*)(ws + 67108864);
    __half* planeHWC = (__half*)(ws + 100663296);

    dim3 cb(64, 4, 1);

    // ---- Level 1: n=128 -> 256, fp32. A: (yl, yh2-LH); B: (yh2-HL, yh2-HH)
    {
        int n = 128, nn = n * n;
        dim3 cg(n / 64, n / 4, 64);
        colpass2_kernel<<<cg, cb, 0, stream>>>(yl, yh2 + 0 * nn, 1.0f, 0.6f, nn, 3 * nn,
                                               yh2 + 1 * nn, yh2 + 2 * nn, 0.6f, 0.6f, 3 * nn, 3 * nn,
                                               n, n, tmpA, tmpB);
        dim3 rg(n / 64, (2 * n) / 4, 32);
        rowpass_kernel<<<rg, cb, 0, stream>>>(tmpA, tmpB, n, llbuf);
    }
    // ---- Level 2: n=256 -> 512, register-blocked col-pass (fp16 tmps), vectorized fp16 rowpass
    {
        int nn = 256 * 256;
        dim3 cg(1, 16, 64);   // x: 64 f4 = full row; 256q / (4thr*4q) = 16; A/B x channels
        colpass4h2c_kernel<<<cg, cb, 0, stream>>>(
            (const float4*)llbuf, (const float4*)(yh1 + 0 * nn), 1.0f, 0.4f, nn / 4, 3 * nn / 4,
            (const float4*)(yh1 + 1 * nn), (const float4*)(yh1 + 2 * nn), 0.4f, 0.4f, 3 * nn / 4, 3 * nn / 4,
            tmpAh, tmpBh);
        // 32c x 512y x 32 q-octets = 524288 threads = 2048 blocks
        rowpass16c_kernel<<<2048, 256, 0, stream>>>(tmpAh, tmpBh, llbuf2h);
    }
    // ---- Level 3: n=512 -> 1024, 8-q-pair colpass (fp16 LL operand), fused HWC rowpass
    {
        int nn = 512 * 512;
        dim3 cg(2, 16, 64);   // x-halves, 512q/(4thr*8q), A/B x channels
        colpass8h2m_kernel<<<cg, cb, 0, stream>>>(
            llbuf2h, (const float4*)(yh0 + 0 * nn), 1.0f, 0.2f, 3 * nn / 4,
            (const float4*)(yh0 + 1 * nn), (const float4*)(yh0 + 2 * nn), 0.2f, 0.2f, 3 * nn / 4, 3 * nn / 4,
            tmpAh, tmpBh);
        dim3 rg(8, 1024);
        rowpass16_hwc_kernel<<<rg, 256, 0, stream>>>(tmpAh, tmpBh, planeHWC);
    }
    // ---- Bilinear sampling: 4 threads/point (empirical floor ~80 us)
    sample_kernel<<<(npts * 4) / 256, 256, 0, stream>>>(pts, planeHWC, (float*)d_out, npts);
}

// Round 15
// 234.031 us; speedup vs baseline: 1.1279x; 1.1279x over previous
//
#include <hip/hip_runtime.h>
#include <hip/hip_bf16.h>
#include <hip/hip_fp16.h>

// coif4 decomposition low-pass filter (L=24), fp32
constexpr int L = 24;
__device__ __constant__ float DEC_LO[L] = {
    -1.7849850030882614e-06f, -3.2596802368833675e-06f, 3.1229875865345646e-05f,
    6.233903446100713e-05f, -0.00025997455248771324f, -0.0005890207562443383f,
    0.0012665619292989445f, 0.003751436157278457f, -0.00565828668661072f,
    -0.015211731527946259f, 0.025082261844864097f, 0.03933442712333749f,
    -0.09622044203398798f, -0.06662747426342504f, 0.4343860564914685f,
    0.782238930920499f, 0.41530840703043026f, -0.05607731331675481f,
    -0.08126669968087875f, 0.026682300156053072f, 0.016068943964776348f,
    -0.0073461663276420935f, -0.0016294920126017326f, 0.0008923136685823146f
};

__device__ __forceinline__ float g0f(int m) { return DEC_LO[23 - m]; }
__device__ __forceinline__ float g1f(int m) { return (m & 1) ? -DEC_LO[m] : DEC_LO[m]; }

// ---------------- L1: merged col-pass (A and B in one dispatch, z selects) ----------------
__global__ void colpass2_kernel(const float* __restrict__ lowA, const float* __restrict__ highA,
                                float sLA, float sHA, int lACS, int hACS,
                                const float* __restrict__ lowB, const float* __restrict__ highB,
                                float sLB, float sHB, int lBCS, int hBCS,
                                int n, int W,
                                float* __restrict__ outA, float* __restrict__ outB)
{
    int x = blockIdx.x * 64 + threadIdx.x;
    int q = blockIdx.y * blockDim.y + threadIdx.y;
    int z = blockIdx.z;
    int c = z & 31;
    bool isB = z >= 32;                  // block-uniform
    const float* low  = isB ? lowB  : lowA;
    const float* high = isB ? highB : highA;
    float sLow  = isB ? sLB : sLA;
    float sHigh = isB ? sHB : sHA;
    int lowCS  = isB ? lBCS : lACS;
    int highCS = isB ? hBCS : hACS;
    float* out = isB ? outB : outA;

    int mask = n - 1;
    const float* lp = low + (size_t)c * lowCS + x;
    const float* hp = high + (size_t)c * highCS + x;
    float a0 = 0.f, a1 = 0.f;
#pragma unroll
    for (int s = 0; s <= 12; ++s) {
        int r = (q + 6 - s) & mask;
        float lv = sLow * lp[(size_t)r * W];
        float hv = sHigh * hp[(size_t)r * W];
        if (s >= 1)  a0 = fmaf(g0f(2 * s - 1), lv, fmaf(g1f(2 * s - 1), hv, a0));
        if (s <= 11) a1 = fmaf(g0f(2 * s), lv, fmaf(g1f(2 * s), hv, a1));
    }
    size_t ob = ((size_t)c * (2 * n) + 2 * q) * W + x;
    out[ob] = a0;
    out[ob + W] = a1;
}

__global__ void rowpass_kernel(const float* __restrict__ lo, const float* __restrict__ hi,
                               int n, float* __restrict__ out)
{
    int q = blockIdx.x * 64 + threadIdx.x;
    int y = blockIdx.y * blockDim.y + threadIdx.y;
    int c = blockIdx.z;
    int N = 2 * n, mask = n - 1;
    const float* lp = lo + ((size_t)c * N + y) * n;
    const float* hp = hi + ((size_t)c * N + y) * n;
    float a0 = 0.f, a1 = 0.f;
#pragma unroll
    for (int s = 0; s <= 12; ++s) {
        int r = (q + 6 - s) & mask;
        float lv = lp[r];
        float hv = hp[r];
        if (s >= 1)  a0 = fmaf(g0f(2 * s - 1), lv, fmaf(g1f(2 * s - 1), hv, a0));
        if (s <= 11) a1 = fmaf(g0f(2 * s), lv, fmaf(g1f(2 * s), hv, a1));
    }
    float2* op = (float2*)(out + ((size_t)c * N + y) * N + 2 * q);
    *op = make_float2(a0, a1);
}

// ---------------- L2 merged col-pass: register-blocked 4 q-pairs/thread, fp32 out ----------------
// n=256 fixed: float4 over x (W4=64), 16-row union window per 4 output-pairs.
__global__ void colpass4f2_kernel(const float4* __restrict__ loA, const float4* __restrict__ hiA,
                                  float sLA, float sHA, int lACS4, int hACS4,
                                  const float4* __restrict__ loB, const float4* __restrict__ hiB,
                                  float sLB, float sHB, int lBCS4, int hBCS4,
                                  float* __restrict__ outA, float* __restrict__ outB)
{
    const int mask = 255, W4 = 64;
    int x = threadIdx.x;                                // [0,64) f4 index, full row
    int q0 = (blockIdx.y * 4 + threadIdx.y) * 4;        // 4 q-pairs per thread
    int z = blockIdx.z;
    int c = z & 31;
    bool isB = z >= 32;
    const float4* lo = isB ? loB : loA;
    const float4* hi = isB ? hiB : hiA;
    float sLow  = isB ? sLB : sLA;
    float sHigh = isB ? sHB : sHA;
    int loCS4 = isB ? lBCS4 : lACS4;
    int hiCS4 = isB ? hBCS4 : hACS4;
    float* out = isB ? outB : outA;

    const float4* lp = lo + (size_t)c * loCS4 + x;
    const float4* hp = hi + (size_t)c * hiCS4 + x;

    float4 a0[4], a1[4];
#pragma unroll
    for (int j = 0; j < 4; ++j) {
        a0[j] = make_float4(0.f, 0.f, 0.f, 0.f);
        a1[j] = make_float4(0.f, 0.f, 0.f, 0.f);
    }
#pragma unroll
    for (int ro = 0; ro < 16; ++ro) {
        int r = (q0 - 6 + ro) & mask;
        float4 lv = lp[(size_t)r * W4];
        float4 hv = hp[(size_t)r * W4];
        lv.x *= sLow;  lv.y *= sLow;  lv.z *= sLow;  lv.w *= sLow;
        hv.x *= sHigh; hv.y *= sHigh; hv.z *= sHigh; hv.w *= sHigh;
#pragma unroll
        for (int j = 0; j < 4; ++j) {
            int s = j + 12 - ro;
            if (s >= 1 && s <= 12) {
                float gl = g0f(2 * s - 1), gh = g1f(2 * s - 1);
                a0[j].x = fmaf(gl, lv.x, fmaf(gh, hv.x, a0[j].x));
                a0[j].y = fmaf(gl, lv.y, fmaf(gh, hv.y, a0[j].y));
                a0[j].z = fmaf(gl, lv.z, fmaf(gh, hv.z, a0[j].z));
                a0[j].w = fmaf(gl, lv.w, fmaf(gh, hv.w, a0[j].w));
            }
            if (s >= 0 && s <= 11) {
                float gl = g0f(2 * s), gh = g1f(2 * s);
                a1[j].x = fmaf(gl, lv.x, fmaf(gh, hv.x, a1[j].x));
                a1[j].y = fmaf(gl, lv.y, fmaf(gh, hv.y, a1[j].y));
                a1[j].z = fmaf(gl, lv.z, fmaf(gh, hv.z, a1[j].z));
                a1[j].w = fmaf(gl, lv.w, fmaf(gh, hv.w, a1[j].w));
            }
        }
    }
#pragma unroll
    for (int j = 0; j < 4; ++j) {
        size_t ob = ((size_t)c * 512 + 2 * (q0 + j)) * 64 + x;   // float4 units
        ((float4*)out)[ob]      = a0[j];
        ((float4*)out)[ob + 64] = a1[j];
    }
}

// ---------------- Level-3 merged col-pass: register-blocked 8 q-pairs/thread ----------------
__global__ void colpass8h2_kernel(const float4* __restrict__ loA, const float4* __restrict__ hiA,
                                  float sLA, float sHA, int lACS4, int hACS4,
                                  const float4* __restrict__ loB, const float4* __restrict__ hiB,
                                  float sLB, float sHB, int lBCS4, int hBCS4,
                                  __half* __restrict__ outA, __half* __restrict__ outB)
{
    const int mask = 511, W4 = 128;
    int x = blockIdx.x * 64 + threadIdx.x;              // float4 index, [0,128)
    int q0 = (blockIdx.y * 4 + threadIdx.y) * 8;        // 8 q-pairs per thread
    int z = blockIdx.z;
    int c = z & 31;
    bool isB = z >= 32;
    const float4* lo = isB ? loB : loA;
    const float4* hi = isB ? hiB : hiA;
    float sLow  = isB ? sLB : sLA;
    float sHigh = isB ? sHB : sHA;
    int loCS4 = isB ? lBCS4 : lACS4;
    int hiCS4 = isB ? hBCS4 : hACS4;
    __half* out = isB ? outB : outA;

    const float4* lp = lo + (size_t)c * loCS4 + x;
    const float4* hp = hi + (size_t)c * hiCS4 + x;

    float4 a0[8], a1[8];
#pragma unroll
    for (int j = 0; j < 8; ++j) {
        a0[j] = make_float4(0.f, 0.f, 0.f, 0.f);
        a1[j] = make_float4(0.f, 0.f, 0.f, 0.f);
    }
    // Union window of rows for q0..q0+7: r = q0-6 .. q0+13 (20 rows).
#pragma unroll
    for (int ro = 0; ro < 20; ++ro) {
        int r = (q0 - 6 + ro) & mask;
        float4 lv = lp[(size_t)r * W4];
        float4 hv = hp[(size_t)r * W4];
        lv.x *= sLow;  lv.y *= sLow;  lv.z *= sLow;  lv.w *= sLow;
        hv.x *= sHigh; hv.y *= sHigh; hv.z *= sHigh; hv.w *= sHigh;
#pragma unroll
        for (int j = 0; j < 8; ++j) {
            int s = j + 12 - ro;
            if (s >= 1 && s <= 12) {
                float gl = g0f(2 * s - 1), gh = g1f(2 * s - 1);
                a0[j].x = fmaf(gl, lv.x, fmaf(gh, hv.x, a0[j].x));
                a0[j].y = fmaf(gl, lv.y, fmaf(gh, hv.y, a0[j].y));
                a0[j].z = fmaf(gl, lv.z, fmaf(gh, hv.z, a0[j].z));
                a0[j].w = fmaf(gl, lv.w, fmaf(gh, hv.w, a0[j].w));
            }
            if (s >= 0 && s <= 11) {
                float gl = g0f(2 * s), gh = g1f(2 * s);
                a1[j].x = fmaf(gl, lv.x, fmaf(gh, hv.x, a1[j].x));
                a1[j].y = fmaf(gl, lv.y, fmaf(gh, hv.y, a1[j].y));
                a1[j].z = fmaf(gl, lv.z, fmaf(gh, hv.z, a1[j].z));
                a1[j].w = fmaf(gl, lv.w, fmaf(gh, hv.w, a1[j].w));
            }
        }
    }
#pragma unroll
    for (int j = 0; j < 8; ++j) {
        size_t ob = ((size_t)c * 1024 + 2 * (q0 + j)) * 512 + 4 * x;
        __half2 p0 = __floats2half2_rn(a0[j].x, a0[j].y), p1 = __floats2half2_rn(a0[j].z, a0[j].w);
        __half2 p2 = __floats2half2_rn(a1[j].x, a1[j].y), p3 = __floats2half2_rn(a1[j].z, a1[j].w);
        *(uint2*)&out[ob]       = make_uint2(*(unsigned int*)&p0, *(unsigned int*)&p1);
        *(uint2*)&out[ob + 512] = make_uint2(*(unsigned int*)&p2, *(unsigned int*)&p3);
    }
}

// ---------------- Level-3 rowpass fused with HWC output ----------------
__global__ void rowpass16_hwc_kernel(const __half* __restrict__ lo, const __half* __restrict__ hi,
                                     __half* __restrict__ out)
{
    const int n = 512, N = 1024, mask = 511;
    int y = blockIdx.y;
    int qb = blockIdx.x * 64;
    int t = threadIdx.x;
    int c = t >> 3;
    int tq = t & 7;
    int q0 = qb + tq * 8;

    const __half* lp = lo + ((size_t)c * N + y) * n;
    const __half* hp = hi + ((size_t)c * N + y) * n;

    float wlo[24], whi[24];
#pragma unroll
    for (int k = 0; k < 3; ++k) {
        int s0 = (q0 - 8 + 8 * k) & mask;
        float4 vl = *(const float4*)(lp + s0);
        float4 vh = *(const float4*)(hp + s0);
        const __half2* hl = (const __half2*)&vl;
        const __half2* hh = (const __half2*)&vh;
#pragma unroll
        for (int j = 0; j < 4; ++j) {
            float2 fl = __half22float2(hl[j]);
            float2 fh = __half22float2(hh[j]);
            wlo[k * 8 + 2 * j]     = fl.x;
            wlo[k * 8 + 2 * j + 1] = fl.y;
            whi[k * 8 + 2 * j]     = fh.x;
            whi[k * 8 + 2 * j + 1] = fh.y;
        }
    }

    __shared__ __half tile[128][34];

#pragma unroll
    for (int j = 0; j < 8; ++j) {
        float a0 = 0.f, a1 = 0.f;
#pragma unroll
        for (int s = 0; s <= 12; ++s) {
            int li = j + 14 - s;
            float lv = wlo[li];
            float hv = whi[li];
            if (s >= 1)  a0 = fmaf(g0f(2 * s - 1), lv, fmaf(g1f(2 * s - 1), hv, a0));
            if (s <= 11) a1 = fmaf(g0f(2 * s), lv, fmaf(g1f(2 * s), hv, a1));
        }
        int pl = 16 * tq + 2 * j;
        tile[pl][c]     = __float2half_rn(a0);
        tile[pl + 1][c] = __float2half_rn(a1);
    }
    __syncthreads();

    int p = t >> 1;
    int c0 = (t & 1) * 16;
    unsigned int w[8];
#pragma unroll
    for (int k = 0; k < 8; ++k) {
        unsigned int l16 = __half_as_ushort(tile[p][c0 + 2 * k]);
        unsigned int h16 = __half_as_ushort(tile[p][c0 + 2 * k + 1]);
        w[k] = l16 | (h16 << 16);
    }
    size_t ob = ((size_t)y * 1024 + 2 * qb + p) * 32 + c0;
    *(uint4*)&out[ob]       = make_uint4(w[0], w[1], w[2], w[3]);
    *(uint4*)(&out[ob + 8]) = make_uint4(w[4], w[5], w[6], w[7]);
}

// ---------------- Sampler: 4 threads/point, 8 channels each (best measured config) ----------------
struct alignas(16) HV { __half2 h[4]; };

__global__ __launch_bounds__(256) void sample_kernel(const float* __restrict__ pts,
                                                     const __half* __restrict__ plane,
                                                     float* __restrict__ out, int npts)
{
    int tid = blockIdx.x * 256 + threadIdx.x;
    int p = tid >> 2, cg = (tid & 3) * 8;
    float2 pt = *(const float2*)(pts + 2 * p);
    float xf = fminf(fmaxf((pt.x + 1.f) * 0.5f * 1023.f, 0.f), 1023.f);
    float yf = fminf(fmaxf((pt.y + 1.f) * 0.5f * 1023.f, 0.f), 1023.f);
    int x0 = (int)xf, y0 = (int)yf;
    int x1 = min(x0 + 1, 1023), y1 = min(y0 + 1, 1023);
    float wx = xf - (float)x0, wy = yf - (float)y0;
    size_t r0 = (size_t)y0 * 1024, r1 = (size_t)y1 * 1024;
    HV v00 = *(const HV*)(plane + (r0 + x0) * 32 + cg);
    HV v01 = *(const HV*)(plane + (r0 + x1) * 32 + cg);
    HV v10 = *(const HV*)(plane + (r1 + x0) * 32 + cg);
    HV v11 = *(const HV*)(plane + (r1 + x1) * 32 + cg);
    float o[8];
#pragma unroll
    for (int k = 0; k < 4; ++k) {
        float2 f00 = __half22float2(v00.h[k]);
        float2 f01 = __half22float2(v01.h[k]);
        float2 f10 = __half22float2(v10.h[k]);
        float2 f11 = __half22float2(v11.h[k]);
        o[2 * k]     = (f00.x * (1.f - wx) + f01.x * wx) * (1.f - wy)
                     + (f10.x * (1.f - wx) + f11.x * wx) * wy;
        o[2 * k + 1] = (f00.y * (1.f - wx) + f01.y * wx) * (1.f - wy)
                     + (f10.y * (1.f - wx) + f11.y * wx) * wy;
    }
    float* ob = out + (size_t)p * 32 + cg;
    *(float4*)ob       = make_float4(o[0], o[1], o[2], o[3]);
    *(float4*)(ob + 4) = make_float4(o[4], o[5], o[6], o[7]);
}

extern "C" void kernel_launch(void* const* d_in, const int* in_sizes, int n_in,
                              void* d_out, int out_size, void* d_ws, size_t ws_size,
                              hipStream_t stream)
{
    const float* pts = (const float*)d_in[0];
    const float* yl  = (const float*)d_in[1];
    const float* yh0 = (const float*)d_in[2]; // (32,3,512,512), scale 0.2, level 3
    const float* yh1 = (const float*)d_in[3]; // (32,3,256,256), scale 0.4, level 2
    const float* yh2 = (const float*)d_in[4]; // (32,3,128,128), scale 0.6, level 1
    const int npts = in_sizes[0] / 2;

    // Workspace layout (bytes), total 167.8 MB:
    //   [0,          33554432)  llbuf    fp32 (up to C x 512 x 512)
    //   [33554432,   67108864)  tmpA     fp32 (L1/L2) / fp16 (L3)
    //   [67108864,  100663296)  tmpB     same
    //   [100663296, 167772160)  planeHWC fp16 (1024,1024,32)
    char* ws = (char*)d_ws;
    float*  llbuf    = (float*)ws;
    float*  tmpA     = (float*)(ws + 33554432);
    float*  tmpB     = (float*)(ws + 67108864);
    __half* tmpAh    = (__half*)(ws + 33554432);
    __half* tmpBh    = (__half*)(ws + 67108864);
    __half* planeHWC = (__half*)(ws + 100663296);

    dim3 cb(64, 4, 1);

    // ---- Level 1: n=128 -> 256. A: (yl, yh2-LH); B: (yh2-HL, yh2-HH)
    {
        int n = 128, nn = n * n;
        dim3 cg(n / 64, n / 4, 64);
        colpass2_kernel<<<cg, cb, 0, stream>>>(yl, yh2 + 0 * nn, 1.0f, 0.6f, nn, 3 * nn,
                                               yh2 + 1 * nn, yh2 + 2 * nn, 0.6f, 0.6f, 3 * nn, 3 * nn,
                                               n, n, tmpA, tmpB);
        dim3 rg(n / 64, (2 * n) / 4, 32);
        rowpass_kernel<<<rg, cb, 0, stream>>>(tmpA, tmpB, n, llbuf);
    }
    // ---- Level 2: n=256 -> 512, register-blocked col-pass (4 q-pairs/thread)
    {
        int n = 256, nn = n * n;
        dim3 cg(1, 16, 64);   // x: 64 f4 = full row; 256q / (4thr*4q) = 16; A/B x channels
        colpass4f2_kernel<<<cg, cb, 0, stream>>>(
            (const float4*)llbuf, (const float4*)(yh1 + 0 * nn), 1.0f, 0.4f, nn / 4, 3 * nn / 4,
            (const float4*)(yh1 + 1 * nn), (const float4*)(yh1 + 2 * nn), 0.4f, 0.4f, 3 * nn / 4, 3 * nn / 4,
            tmpA, tmpB);
        dim3 rg(n / 64, (2 * n) / 4, 32);
        rowpass_kernel<<<rg, cb, 0, stream>>>(tmpA, tmpB, n, llbuf);
    }
    // ---- Level 3: n=512 -> 1024, 8-q-pair register-blocked colpass, fused HWC rowpass
    {
        int nn = 512 * 512;
        dim3 cg(2, 16, 64);   // x-halves, 512q/(4thr*8q), A/B x channels
        colpass8h2_kernel<<<cg, cb, 0, stream>>>(
            (const float4*)llbuf, (const float4*)(yh0 + 0 * nn), 1.0f, 0.2f, nn / 4, 3 * nn / 4,
            (const float4*)(yh0 + 1 * nn), (const float4*)(yh0 + 2 * nn), 0.2f, 0.2f, 3 * nn / 4, 3 * nn / 4,
            tmpAh, tmpBh);
        dim3 rg(8, 1024);
        rowpass16_hwc_kernel<<<rg, 256, 0, stream>>>(tmpAh, tmpBh, planeHWC);
    }
    // ---- Bilinear sampling: 4 threads/point (empirical floor ~80 us)
    sample_kernel<<<(npts * 4) / 256, 256, 0, stream>>>(pts, planeHWC, (float*)d_out, npts);
}